// Round 5
// baseline (208.168 us; speedup 1.0000x reference)
//
#include <hip/hip_runtime.h>
#include <math.h>

// Problem constants (fixed by the reference setup_inputs()).
#define G_NUM   2048
#define N_PTS   65536
#define K_FREQ  8
#define REC     32            // floats per packed gaussian record (128 B)
#define CHUNKS  16            // gaussian list split across gridDim.y
#define G_PER_CHUNK (G_NUM / CHUNKS)
#define PACK_BYTES ((size_t)G_NUM * REC * sizeof(float))          // 256 KiB
#define PART_FLOATS ((size_t)N_PTS * 3)                           // per chunk
#define PART_BYTES  (PART_FLOATS * sizeof(float) * CHUNKS)        // ~12.6 MB

typedef float v2f __attribute__((ext_vector_type(2)));

// v_cos_f32 takes revolutions: cos(2*pi*p). |p| = |f*rx| <= 127*sqrt(2) ~ 180
// is well inside the HW range-reduction domain (+-256).
#if __has_builtin(__builtin_amdgcn_cosf)
__device__ __forceinline__ float hw_cos_rev(float p) { return __builtin_amdgcn_cosf(p); }
#else
__device__ __forceinline__ float hw_cos_rev(float p) { return __cosf(6.28318530717958648f * p); }
#endif
#if __has_builtin(__builtin_amdgcn_exp2f)
__device__ __forceinline__ float hw_exp2(float p) { return __builtin_amdgcn_exp2f(p); }
#else
__device__ __forceinline__ float hw_exp2(float p) { return exp2f(p); }
#endif

// Packed 2-wide fma, scalar multiplier variant -> v_pk_fma_f32.
__device__ __forceinline__ v2f fma2(v2f a, float b, v2f c) {
#if __has_builtin(__builtin_elementwise_fma)
    v2f bb = {b, b};
    return __builtin_elementwise_fma(a, bb, c);
#else
    v2f r; r.x = fmaf(a.x, b, c.x); r.y = fmaf(a.y, b, c.y); return r;
#endif
}
// Packed 2-wide fma, vector multiplier variant.
__device__ __forceinline__ v2f fma2v(v2f a, v2f b, v2f c) {
#if __has_builtin(__builtin_elementwise_fma)
    return __builtin_elementwise_fma(a, b, c);
#else
    v2f r; r.x = fmaf(a.x, b.x, c.x); r.y = fmaf(a.y, b.y, c.y); return r;
#endif
}
__device__ __forceinline__ v2f spread(float b) { v2f r = {b, b}; return r; }

// Record layout (floats):
// [0]=cth [1]=sth [2]=-sth [3]=tx [4]=ty [5]=A [6]=B [7..9]=rgb
// [10..17]=freq_k [18..25]=coef_k [26..31]=pad
// where tx = -(c*px + s*py), ty = s*px - c*py,
//       A = -0.5*log2(e)*sx^2, B = -0.5*log2(e)*sy^2.
// Then rx = c*xi + s*yi + tx, ry = c*yi - s*xi + ty,
//      env = exp2(A*rx^2 + B*ry^2).
__global__ __launch_bounds__(256) void pack_kernel(
    const float* __restrict__ colors, const float* __restrict__ pos,
    const float* __restrict__ scales, const float* __restrict__ rot,
    const float* __restrict__ coef,   const int* __restrict__ idx,
    float* __restrict__ pack)
{
    int j = blockIdx.x * blockDim.x + threadIdx.x;
    if (j >= G_NUM) return;
    float th = rot[j];
    float c = cosf(th), s = sinf(th);
    float px = pos[2 * j], py = pos[2 * j + 1];
    float sx = scales[2 * j], sy = scales[2 * j + 1];
    const float nhl2e = -0.72134752044448170368f;  // -0.5 * log2(e)
    float* r = pack + (size_t)j * REC;
    r[0] = c;
    r[1] = s;
    r[2] = -s;
    r[3] = -(c * px + s * py);
    r[4] = s * px - c * py;
    r[5] = nhl2e * sx * sx;
    r[6] = nhl2e * sy * sy;
    r[7] = colors[3 * j];
    r[8] = colors[3 * j + 1];
    r[9] = colors[3 * j + 2];
#pragma unroll
    for (int k = 0; k < K_FREQ; ++k) {
        // freq = idx * (MAX_FREQ/NUM_TOTAL_FREQ) = idx * 1.0 (revs per rx)
        r[10 + k] = (float)idx[j * K_FREQ + k];
        r[18 + k] = coef[j * K_FREQ + k];
    }
#pragma unroll
    for (int t = 26; t < REC; ++t) r[t] = 0.0f;
}

// 4 points per thread (two <2 x float> packed pairs) x TWO independent
// gaussian streams per thread (j and j+64) -> 16 independent dependency
// chains per SIMD (4 waves x 2 pairs x 2 streams), to test/beat the
// latency bound observed in rounds 3-4 (constant 8 chains -> constant time).
// grid = (N/1024, CHUNKS) = 1024 blocks = 4096 waves = 4 waves/SIMD.
template <bool USE_PART>
__global__ __launch_bounds__(256, 4) void periodic2d_kernel(
    const float* __restrict__ x, const float* __restrict__ pack,
    float* __restrict__ dst /* part buffer or out */)
{
    const int t = blockIdx.x * 256 + threadIdx.x;   // 0 .. N/4-1
    const int p0 = t;
    const int p1 = t + N_PTS / 4;
    const int p2 = t + N_PTS / 2;
    const int p3 = t + 3 * (N_PTS / 4);
    const float2 q0 = ((const float2*)x)[p0];
    const float2 q1 = ((const float2*)x)[p1];
    const float2 q2 = ((const float2*)x)[p2];
    const float2 q3 = ((const float2*)x)[p3];
    const v2f xiA = {q0.x, q1.x}, yiA = {q0.y, q1.y};
    const v2f xiB = {q2.x, q3.x}, yiB = {q2.y, q3.y};
    v2f a0A = {0.f, 0.f}, a1A = {0.f, 0.f}, a2A = {0.f, 0.f};
    v2f a0B = {0.f, 0.f}, a1B = {0.f, 0.f}, a2B = {0.f, 0.f};

    // One gaussian's full update for both point-pairs; shared accumulators.
    auto body = [&](const float* __restrict__ r) {
        const float cth = r[0], sth = r[1], nsth = r[2];
        const float tx = r[3], ty = r[4], A = r[5], B = r[6];
        const v2f rxA = fma2(xiA, cth, fma2(yiA, sth, spread(tx)));
        const v2f rxB = fma2(xiB, cth, fma2(yiB, sth, spread(tx)));
        const v2f ryA = fma2(yiA, cth, fma2(xiA, nsth, spread(ty)));
        const v2f ryB = fma2(yiB, cth, fma2(xiB, nsth, spread(ty)));
        const v2f eargA = fma2v(ryA * B, ryA, (rxA * A) * rxA);
        const v2f eargB = fma2v(ryB * B, ryB, (rxB * A) * rxB);
        v2f envA, envB;
        envA.x = hw_exp2(eargA.x); envA.y = hw_exp2(eargA.y);
        envB.x = hw_exp2(eargB.x); envB.y = hw_exp2(eargB.y);
        // Two partial wave accumulators per pair: fma chain depth 8 -> 4.
        v2f wA0 = {0.f, 0.f}, wA1 = {0.f, 0.f};
        v2f wB0 = {0.f, 0.f}, wB1 = {0.f, 0.f};
#pragma unroll
        for (int k = 0; k < K_FREQ; k += 2) {
            const float f0 = r[10 + k], c0 = r[18 + k];
            const float f1 = r[11 + k], c1 = r[19 + k];
            const v2f phA0 = rxA * f0, phA1 = rxA * f1;
            const v2f phB0 = rxB * f0, phB1 = rxB * f1;
            v2f cA0, cA1, cB0, cB1;
            cA0.x = hw_cos_rev(phA0.x); cA0.y = hw_cos_rev(phA0.y);
            cA1.x = hw_cos_rev(phA1.x); cA1.y = hw_cos_rev(phA1.y);
            cB0.x = hw_cos_rev(phB0.x); cB0.y = hw_cos_rev(phB0.y);
            cB1.x = hw_cos_rev(phB1.x); cB1.y = hw_cos_rev(phB1.y);
            wA0 = fma2(cA0, c0, wA0);  wA1 = fma2(cA1, c1, wA1);
            wB0 = fma2(cB0, c0, wB0);  wB1 = fma2(cB1, c1, wB1);
        }
        const v2f wA = envA * (wA0 + wA1);
        const v2f wB = envB * (wB0 + wB1);
        a0A = fma2(wA, r[7], a0A);  a0B = fma2(wB, r[7], a0B);
        a1A = fma2(wA, r[8], a1A);  a1B = fma2(wB, r[8], a1B);
        a2A = fma2(wA, r[9], a2A);  a2B = fma2(wB, r[9], a2B);
    };

    // Two independent gaussian streams, interleaved for ILP.
    const float* __restrict__ r1 =
        pack + (size_t)(blockIdx.y * G_PER_CHUNK) * REC;
    const float* __restrict__ r2 = r1 + (size_t)(G_PER_CHUNK / 2) * REC;
#pragma unroll 1
    for (int j = 0; j < G_PER_CHUNK / 2; ++j, r1 += REC, r2 += REC) {
        body(r1);
        body(r2);
    }

    if (USE_PART) {
        float* o = dst + (size_t)blockIdx.y * PART_FLOATS;
        o[3 * p0 + 0] = a0A.x; o[3 * p0 + 1] = a1A.x; o[3 * p0 + 2] = a2A.x;
        o[3 * p1 + 0] = a0A.y; o[3 * p1 + 1] = a1A.y; o[3 * p1 + 2] = a2A.y;
        o[3 * p2 + 0] = a0B.x; o[3 * p2 + 1] = a1B.x; o[3 * p2 + 2] = a2B.x;
        o[3 * p3 + 0] = a0B.y; o[3 * p3 + 1] = a1B.y; o[3 * p3 + 2] = a2B.y;
    } else {
        atomicAdd(&dst[3 * p0 + 0], a0A.x);
        atomicAdd(&dst[3 * p0 + 1], a1A.x);
        atomicAdd(&dst[3 * p0 + 2], a2A.x);
        atomicAdd(&dst[3 * p1 + 0], a0A.y);
        atomicAdd(&dst[3 * p1 + 1], a1A.y);
        atomicAdd(&dst[3 * p1 + 2], a2A.y);
        atomicAdd(&dst[3 * p2 + 0], a0B.x);
        atomicAdd(&dst[3 * p2 + 1], a1B.x);
        atomicAdd(&dst[3 * p2 + 2], a2B.x);
        atomicAdd(&dst[3 * p3 + 0], a0B.y);
        atomicAdd(&dst[3 * p3 + 1], a1B.y);
        atomicAdd(&dst[3 * p3 + 2], a2B.y);
    }
}

// Sum the CHUNKS partial slices; float4 per thread.
__global__ __launch_bounds__(256) void reduce_kernel(
    const float* __restrict__ part, float* __restrict__ out)
{
    const int i = blockIdx.x * 256 + threadIdx.x;   // < N_PTS*3/4
    float4 s = {0.f, 0.f, 0.f, 0.f};
#pragma unroll
    for (int c = 0; c < CHUNKS; ++c) {
        const float4 v = ((const float4*)(part + (size_t)c * PART_FLOATS))[i];
        s.x += v.x; s.y += v.y; s.z += v.z; s.w += v.w;
    }
    ((float4*)out)[i] = s;
}

extern "C" void kernel_launch(void* const* d_in, const int* in_sizes, int n_in,
                              void* d_out, int out_size, void* d_ws, size_t ws_size,
                              hipStream_t stream)
{
    const float* x      = (const float*)d_in[0];
    const float* colors = (const float*)d_in[1];
    const float* pos    = (const float*)d_in[2];
    const float* scales = (const float*)d_in[3];
    const float* rot    = (const float*)d_in[4];
    const float* coef   = (const float*)d_in[5];
    const int*   idx    = (const int*)d_in[6];
    float* out  = (float*)d_out;
    float* pack = (float*)d_ws;
    float* part = (float*)((char*)d_ws + PACK_BYTES);

    pack_kernel<<<dim3((G_NUM + 255) / 256), 256, 0, stream>>>(
        colors, pos, scales, rot, coef, idx, pack);

    if (ws_size >= PACK_BYTES + PART_BYTES) {
        periodic2d_kernel<true><<<dim3(N_PTS / 1024, CHUNKS), 256, 0, stream>>>(
            x, pack, part);
        reduce_kernel<<<dim3((N_PTS * 3 / 4) / 256), 256, 0, stream>>>(part, out);
    } else {
        (void)hipMemsetAsync(d_out, 0, (size_t)out_size * sizeof(float), stream);
        periodic2d_kernel<false><<<dim3(N_PTS / 1024, CHUNKS), 256, 0, stream>>>(
            x, pack, out);
    }
}

// Round 6
// 204.598 us; speedup vs baseline: 1.0174x; 1.0174x over previous
//
#include <hip/hip_runtime.h>
#include <math.h>

// Problem constants (fixed by the reference setup_inputs()).
#define G_NUM   2048
#define N_PTS   65536
#define K_FREQ  8
#define REC     64            // floats per record: every scalar DUPLICATED {v,v}
#define CHUNKS  32            // gaussian list split across gridDim.y
#define G_PER_CHUNK (G_NUM / CHUNKS)                              // 64
#define PACK_BYTES ((size_t)G_NUM * REC * sizeof(float))          // 512 KiB
#define PART_FLOATS ((size_t)N_PTS * 3)                           // per chunk
#define PART_BYTES  (PART_FLOATS * sizeof(float) * CHUNKS)        // ~25.2 MB

typedef float v2f __attribute__((ext_vector_type(2)));

// v_cos_f32 takes revolutions: cos(2*pi*p). |p| = |f*rx| <= 127*sqrt(2) ~ 180
// is well inside the HW range-reduction domain (+-256).
#if __has_builtin(__builtin_amdgcn_cosf)
__device__ __forceinline__ float hw_cos_rev(float p) { return __builtin_amdgcn_cosf(p); }
#else
__device__ __forceinline__ float hw_cos_rev(float p) { return __cosf(6.28318530717958648f * p); }
#endif
#if __has_builtin(__builtin_amdgcn_exp2f)
__device__ __forceinline__ float hw_exp2(float p) { return __builtin_amdgcn_exp2f(p); }
#else
__device__ __forceinline__ float hw_exp2(float p) { return exp2f(p); }
#endif

// Packed 2-wide fma -> v_pk_fma_f32. All call sites pass at most ONE
// wave-uniform (SGPR) operand so no v_mov materialization is needed.
__device__ __forceinline__ v2f fma2v(v2f a, v2f b, v2f c) {
#if __has_builtin(__builtin_elementwise_fma)
    return __builtin_elementwise_fma(a, b, c);
#else
    v2f r; r.x = fmaf(a.x, b.x, c.x); r.y = fmaf(a.y, b.y, c.y); return r;
#endif
}

// Record layout in v2f pairs (each pair = {v, v}, even dword offset so an
// SGPR-pair source for VOP3P dual-f32 is properly aligned):
// [0]=px [1]=py [2]=cth [3]=sth [4]=-sth [5]=A [6]=B [7..9]=rgb
// [10..17]=freq_k [18..25]=coef_k [26..31]=pad
// A = -0.5*log2(e)*sx^2, B = -0.5*log2(e)*sy^2; env = exp2(A*rx^2 + B*ry^2).
__global__ __launch_bounds__(256) void pack_kernel(
    const float* __restrict__ colors, const float* __restrict__ pos,
    const float* __restrict__ scales, const float* __restrict__ rot,
    const float* __restrict__ coef,   const int* __restrict__ idx,
    float* __restrict__ pack)
{
    int j = blockIdx.x * blockDim.x + threadIdx.x;
    if (j >= G_NUM) return;
    float th = rot[j];
    float c = cosf(th), s = sinf(th);
    float sx = scales[2 * j], sy = scales[2 * j + 1];
    const float nhl2e = -0.72134752044448170368f;  // -0.5 * log2(e)
    float* r = pack + (size_t)j * REC;
    auto put = [&](int pair, float v) { r[2 * pair] = v; r[2 * pair + 1] = v; };
    put(0, pos[2 * j]);
    put(1, pos[2 * j + 1]);
    put(2, c);
    put(3, s);
    put(4, -s);
    put(5, nhl2e * sx * sx);
    put(6, nhl2e * sy * sy);
    put(7, colors[3 * j]);
    put(8, colors[3 * j + 1]);
    put(9, colors[3 * j + 2]);
#pragma unroll
    for (int k = 0; k < K_FREQ; ++k) {
        // freq = idx * (MAX_FREQ/NUM_TOTAL_FREQ) = idx * 1.0 (revs per rx)
        put(10 + k, (float)idx[j * K_FREQ + k]);
        put(18 + k, coef[j * K_FREQ + k]);
    }
#pragma unroll
    for (int p = 26; p < 32; ++p) put(p, 0.0f);
}

// 4 points per thread (two <2 x float> packed pairs) AND 8 waves/SIMD:
// grid = (N/1024, 32) = 2048 blocks = 8192 waves (full TLP to hide s_load +
// transcendental latency — R5 showed the scheduler won't interleave in-wave
// streams, so parallelism must come from waves). Record reads are wave-
// uniform v2f loads -> s_load; duplicated pairs let VOP3P consume SGPR pairs
// directly (no v_mov broadcast). Every pk op has <=1 uniform operand.
template <bool USE_PART>
__global__ __launch_bounds__(256, 8) void periodic2d_kernel(
    const float* __restrict__ x, const float* __restrict__ pack,
    float* __restrict__ dst /* part buffer or out */)
{
    const int t = blockIdx.x * 256 + threadIdx.x;   // 0 .. N/4-1
    const int p0 = t;
    const int p1 = t + N_PTS / 4;
    const int p2 = t + N_PTS / 2;
    const int p3 = t + 3 * (N_PTS / 4);
    const float2 q0 = ((const float2*)x)[p0];
    const float2 q1 = ((const float2*)x)[p1];
    const float2 q2 = ((const float2*)x)[p2];
    const float2 q3 = ((const float2*)x)[p3];
    const v2f xiA = {q0.x, q1.x}, yiA = {q0.y, q1.y};
    const v2f xiB = {q2.x, q3.x}, yiB = {q2.y, q3.y};
    v2f a0A = {0.f, 0.f}, a1A = {0.f, 0.f}, a2A = {0.f, 0.f};
    v2f a0B = {0.f, 0.f}, a1B = {0.f, 0.f}, a2B = {0.f, 0.f};

    const v2f* __restrict__ rv =
        (const v2f*)(pack + (size_t)(blockIdx.y * G_PER_CHUNK) * REC);
#pragma unroll 1
    for (int j = 0; j < G_PER_CHUNK; ++j, rv += REC / 2) {
        // dx/dy form: every op below reads at most one uniform operand.
        const v2f dxA = xiA - rv[0];
        const v2f dyA = yiA - rv[1];
        const v2f dxB = xiB - rv[0];
        const v2f dyB = yiB - rv[1];
        const v2f rxA = fma2v(dxA, rv[2], dyA * rv[3]);   // c*dx + s*dy
        const v2f rxB = fma2v(dxB, rv[2], dyB * rv[3]);
        const v2f ryA = fma2v(dxA, rv[4], dyA * rv[2]);   // c*dy - s*dx
        const v2f ryB = fma2v(dxB, rv[4], dyB * rv[2]);
        const v2f eargA = fma2v(ryA * rv[6], ryA, (rxA * rv[5]) * rxA);
        const v2f eargB = fma2v(ryB * rv[6], ryB, (rxB * rv[5]) * rxB);
        v2f envA, envB;
        envA.x = hw_exp2(eargA.x); envA.y = hw_exp2(eargA.y);
        envB.x = hw_exp2(eargB.x); envB.y = hw_exp2(eargB.y);
        v2f waveA = {0.f, 0.f}, waveB = {0.f, 0.f};
#pragma unroll
        for (int k = 0; k < K_FREQ; ++k) {
            const v2f phA = rxA * rv[10 + k];
            const v2f phB = rxB * rv[10 + k];
            v2f cA, cB;
            cA.x = hw_cos_rev(phA.x); cA.y = hw_cos_rev(phA.y);
            cB.x = hw_cos_rev(phB.x); cB.y = hw_cos_rev(phB.y);
            waveA = fma2v(cA, rv[18 + k], waveA);
            waveB = fma2v(cB, rv[18 + k], waveB);
        }
        const v2f wA = envA * waveA;
        const v2f wB = envB * waveB;
        a0A = fma2v(wA, rv[7], a0A);  a0B = fma2v(wB, rv[7], a0B);
        a1A = fma2v(wA, rv[8], a1A);  a1B = fma2v(wB, rv[8], a1B);
        a2A = fma2v(wA, rv[9], a2A);  a2B = fma2v(wB, rv[9], a2B);
    }

    if (USE_PART) {
        float* o = dst + (size_t)blockIdx.y * PART_FLOATS;
        o[3 * p0 + 0] = a0A.x; o[3 * p0 + 1] = a1A.x; o[3 * p0 + 2] = a2A.x;
        o[3 * p1 + 0] = a0A.y; o[3 * p1 + 1] = a1A.y; o[3 * p1 + 2] = a2A.y;
        o[3 * p2 + 0] = a0B.x; o[3 * p2 + 1] = a1B.x; o[3 * p2 + 2] = a2B.x;
        o[3 * p3 + 0] = a0B.y; o[3 * p3 + 1] = a1B.y; o[3 * p3 + 2] = a2B.y;
    } else {
        atomicAdd(&dst[3 * p0 + 0], a0A.x);
        atomicAdd(&dst[3 * p0 + 1], a1A.x);
        atomicAdd(&dst[3 * p0 + 2], a2A.x);
        atomicAdd(&dst[3 * p1 + 0], a0A.y);
        atomicAdd(&dst[3 * p1 + 1], a1A.y);
        atomicAdd(&dst[3 * p1 + 2], a2A.y);
        atomicAdd(&dst[3 * p2 + 0], a0B.x);
        atomicAdd(&dst[3 * p2 + 1], a1B.x);
        atomicAdd(&dst[3 * p2 + 2], a2B.x);
        atomicAdd(&dst[3 * p3 + 0], a0B.y);
        atomicAdd(&dst[3 * p3 + 1], a1B.y);
        atomicAdd(&dst[3 * p3 + 2], a2B.y);
    }
}

// Sum the CHUNKS partial slices; float4 per thread.
__global__ __launch_bounds__(256) void reduce_kernel(
    const float* __restrict__ part, float* __restrict__ out)
{
    const int i = blockIdx.x * 256 + threadIdx.x;   // < N_PTS*3/4
    float4 s = {0.f, 0.f, 0.f, 0.f};
#pragma unroll
    for (int c = 0; c < CHUNKS; ++c) {
        const float4 v = ((const float4*)(part + (size_t)c * PART_FLOATS))[i];
        s.x += v.x; s.y += v.y; s.z += v.z; s.w += v.w;
    }
    ((float4*)out)[i] = s;
}

extern "C" void kernel_launch(void* const* d_in, const int* in_sizes, int n_in,
                              void* d_out, int out_size, void* d_ws, size_t ws_size,
                              hipStream_t stream)
{
    const float* x      = (const float*)d_in[0];
    const float* colors = (const float*)d_in[1];
    const float* pos    = (const float*)d_in[2];
    const float* scales = (const float*)d_in[3];
    const float* rot    = (const float*)d_in[4];
    const float* coef   = (const float*)d_in[5];
    const int*   idx    = (const int*)d_in[6];
    float* out  = (float*)d_out;
    float* pack = (float*)d_ws;
    float* part = (float*)((char*)d_ws + PACK_BYTES);

    pack_kernel<<<dim3((G_NUM + 255) / 256), 256, 0, stream>>>(
        colors, pos, scales, rot, coef, idx, pack);

    if (ws_size >= PACK_BYTES + PART_BYTES) {
        periodic2d_kernel<true><<<dim3(N_PTS / 1024, CHUNKS), 256, 0, stream>>>(
            x, pack, part);
        reduce_kernel<<<dim3((N_PTS * 3 / 4) / 256), 256, 0, stream>>>(part, out);
    } else {
        (void)hipMemsetAsync(d_out, 0, (size_t)out_size * sizeof(float), stream);
        periodic2d_kernel<false><<<dim3(N_PTS / 1024, CHUNKS), 256, 0, stream>>>(
            x, pack, out);
    }
}